// Round 16
// baseline (15121.283 us; speedup 1.0000x reference)
//
#include <hip/hip_runtime.h>
#include <hip/hip_bf16.h>

// v16 = v12 exchange (8-replica tagged h, append-only y0 log, no fences)
// with the step skeleton restructured:
//  - slot-per-unit dots: L0 16 slots x 32 lanes (3 rows), L1 8 slots x 64
//    lanes (6 rows: whh + wih) -> group leader holds ALL gate terms in-lane.
//  - no lds_gh, no S1 barrier: ONE __syncthreads per step.
//  - lds_h / lds_y parity double-buffered (poll writes (t+1)&1, dot reads t&1).
//  - L1 y-staging merged into the poll (4-concurrent tagged loads).
//  - s_setprio(1) around gates+publish.

#define TT    4096
#define HDIM  1024
#define L0WG  64
#define L1WG  128
#define SBS   512
#define NREP  8
typedef unsigned long long u64;

// ---------------- embedding gather ----------------
__global__ void embed_kernel(const int* __restrict__ idx,
                             const float* __restrict__ emb,
                             float* __restrict__ x) {
    int t = blockIdx.x;
    int row = idx[t];
    const float4* src = reinterpret_cast<const float4*>(emb + (size_t)row * HDIM);
    float4* dst = reinterpret_cast<float4*>(x + (size_t)t * HDIM);
    dst[threadIdx.x] = src[threadIdx.x];
}

// ---------------- fp32 NT GEMM (gi0) ----------------
#define BM 64
#define BN 64
#define BK 32
__global__ __launch_bounds__(256)
void gemm_nt_bias(const float* __restrict__ A,
                  const float* __restrict__ Bw,
                  const float* __restrict__ bias,
                  float* __restrict__ C,
                  int M, int N, int K) {
    __shared__ float As[BK][BM];
    __shared__ float Bs[BK][BN];
    const int tid = threadIdx.x;
    const int m0 = blockIdx.x * BM;
    const int n0 = blockIdx.y * BN;
    const int tx = tid & 15, ty = tid >> 4;
    const int lr = tid >> 3;
    const int lc = (tid & 7) * 4;

    float acc[4][4] = {};

    for (int k0 = 0; k0 < K; k0 += BK) {
#pragma unroll
        for (int pass = 0; pass < 2; ++pass) {
            int m = lr + pass * 32;
            float4 v = *reinterpret_cast<const float4*>(A + (size_t)(m0 + m) * K + k0 + lc);
            As[lc + 0][m] = v.x; As[lc + 1][m] = v.y;
            As[lc + 2][m] = v.z; As[lc + 3][m] = v.w;
            float4 u = *reinterpret_cast<const float4*>(Bw + (size_t)(n0 + m) * K + k0 + lc);
            Bs[lc + 0][m] = u.x; Bs[lc + 1][m] = u.y;
            Bs[lc + 2][m] = u.z; Bs[lc + 3][m] = u.w;
        }
        __syncthreads();
#pragma unroll
        for (int kk = 0; kk < BK; ++kk) {
            float4 a = *reinterpret_cast<const float4*>(&As[kk][ty * 4]);
            float4 b = *reinterpret_cast<const float4*>(&Bs[kk][tx * 4]);
            float av[4] = {a.x, a.y, a.z, a.w};
            float bv[4] = {b.x, b.y, b.z, b.w};
#pragma unroll
            for (int i = 0; i < 4; ++i)
#pragma unroll
                for (int j = 0; j < 4; ++j)
                    acc[i][j] = fmaf(av[i], bv[j], acc[i][j]);
        }
        __syncthreads();
    }

    float4 b4 = *reinterpret_cast<const float4*>(bias + n0 + tx * 4);
    float bb[4] = {b4.x, b4.y, b4.z, b4.w};
#pragma unroll
    for (int i = 0; i < 4; ++i) {
        int m = m0 + ty * 4 + i;
        float4 o;
        o.x = acc[i][0] + bb[0];
        o.y = acc[i][1] + bb[1];
        o.z = acc[i][2] + bb[2];
        o.w = acc[i][3] + bb[3];
        *reinterpret_cast<float4*>(C + (size_t)m * N + n0 + tx * 4) = o;
    }
}

// ---------------- helpers ----------------
__device__ __forceinline__ float dot4(float4 a, float4 b) {
    return fmaf(a.x, b.x, fmaf(a.y, b.y, fmaf(a.z, b.z, a.w * b.w)));
}
__device__ __forceinline__ float fsig(float x) { return 1.f / (1.f + __expf(-x)); }
__device__ __forceinline__ float ftanh(float x) {
    return fmaf(-2.f, 1.f / (1.f + __expf(2.f * x)), 1.f);
}
__device__ __forceinline__ u64 pack_h(unsigned seq, float h) {
    return ((u64)seq << 32) | (u64)__float_as_uint(h);
}
__device__ __forceinline__ u64 aload(const u64* p) {
    return __hip_atomic_load(p, __ATOMIC_RELAXED, __HIP_MEMORY_SCOPE_AGENT);
}
__device__ __forceinline__ void poll2(const u64* p0, const u64* p1, unsigned need,
                                      u64& v0, u64& v1) {
    v0 = aload(p0);
    v1 = aload(p1);
    while ((unsigned)(v0 >> 32) < need || (unsigned)(v1 >> 32) < need) {
        v0 = aload(p0);
        v1 = aload(p1);
    }
}
__device__ __forceinline__ void poll4(const u64* p0, const u64* p1, unsigned needh,
                                      const u64* p2, const u64* p3, unsigned needy,
                                      u64& v0, u64& v1, u64& v2, u64& v3) {
    v0 = aload(p0); v1 = aload(p1); v2 = aload(p2); v3 = aload(p3);
    while ((unsigned)(v0 >> 32) < needh || (unsigned)(v1 >> 32) < needh ||
           (unsigned)(v2 >> 32) < needy || (unsigned)(v3 >> 32) < needy) {
        v0 = aload(p0); v1 = aload(p1); v2 = aload(p2); v3 = aload(p3);
    }
}
__device__ __forceinline__ void pub_h(u64* rep, int par, int idx, u64 v) {
#pragma unroll
    for (int r = 0; r < NREP; ++r)
        __hip_atomic_store(rep + ((size_t)r * 2 + par) * HDIM + idx, v,
                           __ATOMIC_RELAXED, __HIP_MEMORY_SCOPE_AGENT);
}

// ---------------- fused pipelined scan v16 ----------------
__global__ __launch_bounds__(SBS, 1)
void gru_pipe(const float* __restrict__ gi0,
              const float* __restrict__ whh0,
              const float* __restrict__ bhh0,
              const float* __restrict__ wih1,
              const float* __restrict__ whh1,
              const float* __restrict__ bih1,
              const float* __restrict__ bhh1,
              u64* y0log,                  // [T][HDIM] tagged, append-only
              float* __restrict__ out,     // [T*H + 2H]
              u64* h0rep, u64* h1rep) {    // [NREP][2][HDIM] tagged
    const int tid = threadIdx.x;
    const int xcd = blockIdx.x & 7;

    __shared__ __align__(16) float lds_h[2][HDIM];
    __shared__ __align__(16) float lds_y[2][HDIM];

    if (blockIdx.x < L0WG) {
        // ========== layer 0: 16 slots x 32 lanes, 3 rows per slot ==========
        const int g = blockIdx.x;
        const int l = tid & 31;
        const int u = g * 16 + (tid >> 5);

        const float4* r0 = reinterpret_cast<const float4*>(whh0 + (size_t)(0 * HDIM + u) * HDIM);
        const float4* r1 = reinterpret_cast<const float4*>(whh0 + (size_t)(1 * HDIM + u) * HDIM);
        const float4* r2 = reinterpret_cast<const float4*>(whh0 + (size_t)(2 * HDIM + u) * HDIM);
        float4 W0[8], W1[8], W2[8];
#pragma unroll
        for (int m = 0; m < 8; ++m) {
            W0[m] = r0[m * 32 + l];
            W1[m] = r1[m * 32 + l];
            W2[m] = r2[m * 32 + l];
        }

        float bh0 = 0.f, bh1 = 0.f, bh2 = 0.f;
        float gir = 0.f, giz = 0.f, gin = 0.f;
        float h_own = 0.f;
        if (l == 0) {
            bh0 = bhh0[u]; bh1 = bhh0[HDIM + u]; bh2 = bhh0[2 * HDIM + u];
            gir = gi0[u];  giz = gi0[HDIM + u];  gin = gi0[2 * HDIM + u];
        }

        reinterpret_cast<float2*>(lds_h[0])[tid] = float2{0.f, 0.f};
        __syncthreads();

        for (int t = 0; t < TT; ++t) {
            const float4* lh4 = reinterpret_cast<const float4*>(lds_h[t & 1]);
            float p0 = 0.f, p1 = 0.f, p2 = 0.f;
#pragma unroll
            for (int m = 0; m < 8; ++m) {
                const float4 h4 = lh4[m * 32 + l];
                p0 += dot4(W0[m], h4);
                p1 += dot4(W1[m], h4);
                p2 += dot4(W2[m], h4);
            }
#pragma unroll
            for (int o = 1; o < 32; o <<= 1) {
                p0 += __shfl_xor(p0, o);
                p1 += __shfl_xor(p1, o);
                p2 += __shfl_xor(p2, o);
            }

            if (l == 0) {
                __builtin_amdgcn_s_setprio(1);
                const float r = fsig(gir + p0 + bh0);
                const float z = fsig(giz + p1 + bh1);
                const float n = ftanh(gin + r * (p2 + bh2));
                const float h_new = (1.f - z) * n + z * h_own;
                h_own = h_new;
                const u64 pk = pack_h((unsigned)(t + 1), h_new);
                pub_h(h0rep, (t + 1) & 1, u, pk);
                __hip_atomic_store(y0log + (size_t)t * HDIM + u, pk,
                                   __ATOMIC_RELAXED, __HIP_MEMORY_SCOPE_AGENT);
                __builtin_amdgcn_s_setprio(0);
                if (t == TT - 1) out[(size_t)TT * HDIM + u] = h_new;
                if (t + 1 < TT) {
                    const float* b = gi0 + (size_t)(t + 1) * 3 * HDIM + u;
                    gir = b[0]; giz = b[HDIM]; gin = b[2 * HDIM];
                }
            }

            if (t + 1 < TT) {
                const unsigned need = (unsigned)(t + 1);
                const u64* hp = h0rep + ((size_t)xcd * 2 + ((t + 1) & 1)) * HDIM;
                u64 v0, v1;
                poll2(hp + 2 * tid, hp + 2 * tid + 1, need, v0, v1);
                float2 hv;
                hv.x = __uint_as_float((unsigned)v0);
                hv.y = __uint_as_float((unsigned)v1);
                reinterpret_cast<float2*>(lds_h[(t + 1) & 1])[tid] = hv;
            }
            __syncthreads();
        }
    } else {
        // ========== layer 1: 8 slots x 64 lanes, 6 rows per slot ==========
        const int g1 = blockIdx.x - L0WG;
        const int l = tid & 63;
        const int u = g1 * 8 + (tid >> 6);

        const float4* rh0 = reinterpret_cast<const float4*>(whh1 + (size_t)(0 * HDIM + u) * HDIM);
        const float4* rh1 = reinterpret_cast<const float4*>(whh1 + (size_t)(1 * HDIM + u) * HDIM);
        const float4* rh2 = reinterpret_cast<const float4*>(whh1 + (size_t)(2 * HDIM + u) * HDIM);
        const float4* ri0 = reinterpret_cast<const float4*>(wih1 + (size_t)(0 * HDIM + u) * HDIM);
        const float4* ri1 = reinterpret_cast<const float4*>(wih1 + (size_t)(1 * HDIM + u) * HDIM);
        const float4* ri2 = reinterpret_cast<const float4*>(wih1 + (size_t)(2 * HDIM + u) * HDIM);
        float4 WH0[4], WH1[4], WH2[4], WI0[4], WI1[4], WI2[4];
#pragma unroll
        for (int m = 0; m < 4; ++m) {
            WH0[m] = rh0[m * 64 + l]; WH1[m] = rh1[m * 64 + l]; WH2[m] = rh2[m * 64 + l];
            WI0[m] = ri0[m * 64 + l]; WI1[m] = ri1[m * 64 + l]; WI2[m] = ri2[m * 64 + l];
        }

        float bh0 = 0.f, bh1 = 0.f, bh2 = 0.f;
        float bi0 = 0.f, bi1 = 0.f, bi2 = 0.f;
        float h_own = 0.f;
        if (l == 0) {
            bh0 = bhh1[u]; bh1 = bhh1[HDIM + u]; bh2 = bhh1[2 * HDIM + u];
            bi0 = bih1[u]; bi1 = bih1[HDIM + u]; bi2 = bih1[2 * HDIM + u];
        }

        reinterpret_cast<float2*>(lds_h[0])[tid] = float2{0.f, 0.f};
        // prologue: stage y(0) (waits for L0 step 0)
        {
            u64 v0, v1;
            poll2(y0log + 2 * tid, y0log + 2 * tid + 1, 1u, v0, v1);
            float2 yv;
            yv.x = __uint_as_float((unsigned)v0);
            yv.y = __uint_as_float((unsigned)v1);
            reinterpret_cast<float2*>(lds_y[0])[tid] = yv;
        }
        __syncthreads();

        for (int t = 0; t < TT; ++t) {
            const float4* lh4 = reinterpret_cast<const float4*>(lds_h[t & 1]);
            const float4* ly4 = reinterpret_cast<const float4*>(lds_y[t & 1]);
            float ph0 = 0.f, ph1 = 0.f, ph2 = 0.f;
            float pi0 = 0.f, pi1 = 0.f, pi2 = 0.f;
#pragma unroll
            for (int m = 0; m < 4; ++m) {
                const float4 h4 = lh4[m * 64 + l];
                const float4 y4 = ly4[m * 64 + l];
                ph0 += dot4(WH0[m], h4);
                ph1 += dot4(WH1[m], h4);
                ph2 += dot4(WH2[m], h4);
                pi0 += dot4(WI0[m], y4);
                pi1 += dot4(WI1[m], y4);
                pi2 += dot4(WI2[m], y4);
            }
#pragma unroll
            for (int o = 1; o < 64; o <<= 1) {
                ph0 += __shfl_xor(ph0, o);
                ph1 += __shfl_xor(ph1, o);
                ph2 += __shfl_xor(ph2, o);
                pi0 += __shfl_xor(pi0, o);
                pi1 += __shfl_xor(pi1, o);
                pi2 += __shfl_xor(pi2, o);
            }

            if (l == 0) {
                __builtin_amdgcn_s_setprio(1);
                const float r = fsig(pi0 + bi0 + ph0 + bh0);
                const float z = fsig(pi1 + bi1 + ph1 + bh1);
                const float n = ftanh(pi2 + bi2 + r * (ph2 + bh2));
                const float h_new = (1.f - z) * n + z * h_own;
                h_own = h_new;
                pub_h(h1rep, (t + 1) & 1, u, pack_h((unsigned)(t + 1), h_new));
                __builtin_amdgcn_s_setprio(0);
                out[(size_t)t * HDIM + u] = h_new;
                if (t == TT - 1) out[(size_t)TT * HDIM + HDIM + u] = h_new;
            }

            if (t + 1 < TT) {
                const unsigned needh = (unsigned)(t + 1);
                const unsigned needy = (unsigned)(t + 2);
                const u64* hp = h1rep + ((size_t)xcd * 2 + ((t + 1) & 1)) * HDIM;
                const u64* yp = y0log + (size_t)(t + 1) * HDIM;
                u64 v0, v1, v2, v3;
                poll4(hp + 2 * tid, hp + 2 * tid + 1, needh,
                      yp + 2 * tid, yp + 2 * tid + 1, needy, v0, v1, v2, v3);
                float2 hv, yv;
                hv.x = __uint_as_float((unsigned)v0);
                hv.y = __uint_as_float((unsigned)v1);
                yv.x = __uint_as_float((unsigned)v2);
                yv.y = __uint_as_float((unsigned)v3);
                reinterpret_cast<float2*>(lds_h[(t + 1) & 1])[tid] = hv;
                reinterpret_cast<float2*>(lds_y[(t + 1) & 1])[tid] = yv;
            }
            __syncthreads();
        }
    }
}

// ---------------- launch ----------------
extern "C" void kernel_launch(void* const* d_in, const int* in_sizes, int n_in,
                              void* d_out, int out_size, void* d_ws, size_t ws_size,
                              hipStream_t stream) {
    const int*   idx = (const int*)d_in[0];
    const float* emb = (const float*)d_in[1];
    const float* wih = (const float*)d_in[2];
    const float* whh = (const float*)d_in[3];
    const float* bih = (const float*)d_in[4];
    const float* bhh = (const float*)d_in[5];
    float* out = (float*)d_out;

    float* x     = (float*)d_ws;                 // [T,H]
    float* gi    = x  + (size_t)TT * HDIM;       // [T,3H]
    u64*   y0log = (u64*)(gi + (size_t)TT * 3 * HDIM);   // [T][H] tagged
    u64*   h0rep = y0log + (size_t)TT * HDIM;            // [NREP][2][H]
    u64*   h1rep = h0rep + (size_t)NREP * 2 * HDIM;      // [NREP][2][H]
    size_t zero_bytes = ((size_t)TT * HDIM + 2 * (size_t)NREP * 2 * HDIM) * 8;

    hipMemsetAsync(y0log, 0, zero_bytes, stream);

    embed_kernel<<<TT, 256, 0, stream>>>(idx, emb, x);

    const size_t wstride = (size_t)3 * HDIM * HDIM;
    const size_t bstride = (size_t)3 * HDIM;

    gemm_nt_bias<<<dim3(TT / BM, 3 * HDIM / BN), 256, 0, stream>>>(
        x, wih, bih, gi, TT, 3 * HDIM, HDIM);

    gru_pipe<<<L0WG + L1WG, SBS, 0, stream>>>(
        gi, whh, bhh,
        wih + wstride, whh + wstride, bih + bstride, bhh + bstride,
        y0log, out, h0rep, h1rep);
}

// Round 17
// 10620.795 us; speedup vs baseline: 1.4237x; 1.4237x over previous
//
#include <hip/hip_runtime.h>
#include <hip/hip_bf16.h>

// v17 = v12 (best: 10.08ms) + critical-lane poll exemption + setprio.
//  - gate lanes (L0 tid<16, L1 tid<8) and L1's y-stager wave (tid>=448)
//    do NOT poll h; their words are redistributed as a 3rd concurrent
//    poll word on other lanes (detect is set by last-publish, not count).
//  - s_setprio(1) around gates+publish (prioritize vs spinning pollers).
//  - everything else v12 verbatim: coalesced single-wave publish, 8-replica
//    tagged h + poll2/poll3, append-only y0 log, no fences, f32 weights.

#define TT    4096
#define HDIM  1024
#define L0WG  64
#define L1WG  128
#define SBS   512
#define NREP  8
typedef unsigned long long u64;

// ---------------- embedding gather ----------------
__global__ void embed_kernel(const int* __restrict__ idx,
                             const float* __restrict__ emb,
                             float* __restrict__ x) {
    int t = blockIdx.x;
    int row = idx[t];
    const float4* src = reinterpret_cast<const float4*>(emb + (size_t)row * HDIM);
    float4* dst = reinterpret_cast<float4*>(x + (size_t)t * HDIM);
    dst[threadIdx.x] = src[threadIdx.x];
}

// ---------------- fp32 NT GEMM (gi0) ----------------
#define BM 64
#define BN 64
#define BK 32
__global__ __launch_bounds__(256)
void gemm_nt_bias(const float* __restrict__ A,
                  const float* __restrict__ Bw,
                  const float* __restrict__ bias,
                  float* __restrict__ C,
                  int M, int N, int K) {
    __shared__ float As[BK][BM];
    __shared__ float Bs[BK][BN];
    const int tid = threadIdx.x;
    const int m0 = blockIdx.x * BM;
    const int n0 = blockIdx.y * BN;
    const int tx = tid & 15, ty = tid >> 4;
    const int lr = tid >> 3;
    const int lc = (tid & 7) * 4;

    float acc[4][4] = {};

    for (int k0 = 0; k0 < K; k0 += BK) {
#pragma unroll
        for (int pass = 0; pass < 2; ++pass) {
            int m = lr + pass * 32;
            float4 v = *reinterpret_cast<const float4*>(A + (size_t)(m0 + m) * K + k0 + lc);
            As[lc + 0][m] = v.x; As[lc + 1][m] = v.y;
            As[lc + 2][m] = v.z; As[lc + 3][m] = v.w;
            float4 u = *reinterpret_cast<const float4*>(Bw + (size_t)(n0 + m) * K + k0 + lc);
            Bs[lc + 0][m] = u.x; Bs[lc + 1][m] = u.y;
            Bs[lc + 2][m] = u.z; Bs[lc + 3][m] = u.w;
        }
        __syncthreads();
#pragma unroll
        for (int kk = 0; kk < BK; ++kk) {
            float4 a = *reinterpret_cast<const float4*>(&As[kk][ty * 4]);
            float4 b = *reinterpret_cast<const float4*>(&Bs[kk][tx * 4]);
            float av[4] = {a.x, a.y, a.z, a.w};
            float bv[4] = {b.x, b.y, b.z, b.w};
#pragma unroll
            for (int i = 0; i < 4; ++i)
#pragma unroll
                for (int j = 0; j < 4; ++j)
                    acc[i][j] = fmaf(av[i], bv[j], acc[i][j]);
        }
        __syncthreads();
    }

    float4 b4 = *reinterpret_cast<const float4*>(bias + n0 + tx * 4);
    float bb[4] = {b4.x, b4.y, b4.z, b4.w};
#pragma unroll
    for (int i = 0; i < 4; ++i) {
        int m = m0 + ty * 4 + i;
        float4 o;
        o.x = acc[i][0] + bb[0];
        o.y = acc[i][1] + bb[1];
        o.z = acc[i][2] + bb[2];
        o.w = acc[i][3] + bb[3];
        *reinterpret_cast<float4*>(C + (size_t)m * N + n0 + tx * 4) = o;
    }
}

// ---------------- helpers ----------------
__device__ __forceinline__ float dot4(float4 a, float4 b) {
    return fmaf(a.x, b.x, fmaf(a.y, b.y, fmaf(a.z, b.z, a.w * b.w)));
}
__device__ __forceinline__ float fsig(float x) { return 1.f / (1.f + __expf(-x)); }
__device__ __forceinline__ float ftanh(float x) {
    return fmaf(-2.f, 1.f / (1.f + __expf(2.f * x)), 1.f);
}
__device__ __forceinline__ u64 pack_h(unsigned seq, float h) {
    return ((u64)seq << 32) | (u64)__float_as_uint(h);
}
__device__ __forceinline__ u64 aload(const u64* p) {
    return __hip_atomic_load(p, __ATOMIC_RELAXED, __HIP_MEMORY_SCOPE_AGENT);
}
__device__ __forceinline__ u64 poll_h(const u64* p, unsigned need) {
    u64 v = aload(p);
    while ((unsigned)(v >> 32) < need) v = aload(p);
    return v;
}
// 2- and 3-word concurrent polls (all loads in flight each retry round)
__device__ __forceinline__ void poll2(const u64* p0, const u64* p1, unsigned need,
                                      u64& v0, u64& v1) {
    v0 = aload(p0);
    v1 = aload(p1);
    while ((unsigned)(v0 >> 32) < need || (unsigned)(v1 >> 32) < need) {
        v0 = aload(p0);
        v1 = aload(p1);
    }
}
__device__ __forceinline__ void poll3(const u64* p0, const u64* p1, const u64* p2,
                                      unsigned need, u64& v0, u64& v1, u64& v2) {
    v0 = aload(p0);
    v1 = aload(p1);
    v2 = aload(p2);
    while ((unsigned)(v0 >> 32) < need || (unsigned)(v1 >> 32) < need ||
           (unsigned)(v2 >> 32) < need) {
        v0 = aload(p0);
        v1 = aload(p1);
        v2 = aload(p2);
    }
}
__device__ __forceinline__ void pub_h(u64* rep, int par, int idx, u64 v) {
#pragma unroll
    for (int r = 0; r < NREP; ++r)
        __hip_atomic_store(rep + ((size_t)r * 2 + par) * HDIM + idx, v,
                           __ATOMIC_RELAXED, __HIP_MEMORY_SCOPE_AGENT);
}
// stage a full y-row from the tagged log into lds (lane l owns k*64+l)
__device__ __forceinline__ void stage_y(const u64* lrow, unsigned need,
                                        float* lds_y, int l) {
    u64 v[16];
#pragma unroll
    for (int k = 0; k < 16; ++k) v[k] = aload(lrow + k * 64 + l);
#pragma unroll
    for (int k = 0; k < 16; ++k)
        while ((unsigned)(v[k] >> 32) < need) v[k] = aload(lrow + k * 64 + l);
#pragma unroll
    for (int k = 0; k < 16; ++k)
        lds_y[k * 64 + l] = __uint_as_float((unsigned)v[k]);
}

// ---------------- fused pipelined scan v17 ----------------
__global__ __launch_bounds__(SBS, 1)
void gru_pipe(const float* __restrict__ gi0,
              const float* __restrict__ whh0,
              const float* __restrict__ bhh0,
              const float* __restrict__ wih1,
              const float* __restrict__ whh1,
              const float* __restrict__ bih1,
              const float* __restrict__ bhh1,
              u64* y0log,                  // [T][HDIM] tagged, append-only
              float* __restrict__ out,     // [T*H + 2H]
              u64* h0rep, u64* h1rep) {    // [NREP][2][HDIM] tagged
    const int tid  = threadIdx.x;
    const int slot = tid >> 3;
    const int l8   = tid & 7;
    const int xcd  = blockIdx.x & 7;

    __shared__ float lds_h[HDIM];
    __shared__ float lds_y[HDIM];
    __shared__ float lds_gh[48];

    if (blockIdx.x < L0WG) {
        // ================= layer 0 (16 units/WG) =================
        const int g = blockIdx.x;

        float4 Wlo[16], Whi[16];
        if (slot < 48) {
            const int q = slot >> 4, jl = slot & 15;
            const float4* row4 = reinterpret_cast<const float4*>(
                whh0 + (size_t)(q * HDIM + g * 16 + jl) * HDIM);
#pragma unroll
            for (int k4 = 0; k4 < 16; ++k4) Wlo[k4] = row4[k4 * 8 + l8];
#pragma unroll
            for (int k4 = 0; k4 < 16; ++k4) Whi[k4] = row4[(k4 + 16) * 8 + l8];
        } else {
#pragma unroll
            for (int k4 = 0; k4 < 16; ++k4) { Wlo[k4] = float4{0,0,0,0}; Whi[k4] = float4{0,0,0,0}; }
        }

        float bh0 = 0.f, bh1 = 0.f, bh2 = 0.f;
        float gir = 0.f, giz = 0.f, gin = 0.f;
        float h_own = 0.f;
        if (tid < 16) {
            const int gj = g * 16 + tid;
            bh0 = bhh0[0 * HDIM + gj];
            bh1 = bhh0[1 * HDIM + gj];
            bh2 = bhh0[2 * HDIM + gj];
            gir = gi0[gj];
            giz = gi0[HDIM + gj];
            gin = gi0[2 * HDIM + gj];
        }

        lds_h[tid] = 0.f;
        lds_h[tid + SBS] = 0.f;
        __syncthreads();

        const float4* lh4 = reinterpret_cast<const float4*>(lds_h);

        for (int t = 0; t < TT; ++t) {
            float nir = 0.f, niz = 0.f, nin = 0.f;
            if (tid < 16 && t + 1 < TT) {
                const float* base = gi0 + (size_t)(t + 1) * 3 * HDIM + g * 16 + tid;
                nir = base[0];
                niz = base[HDIM];
                nin = base[2 * HDIM];
            }

            if (slot < 48) {
                float p0 = 0.f, p1 = 0.f;
#pragma unroll
                for (int k4 = 0; k4 < 16; ++k4) p0 += dot4(Wlo[k4], lh4[k4 * 8 + l8]);
#pragma unroll
                for (int k4 = 0; k4 < 16; ++k4) p1 += dot4(Whi[k4], lh4[(k4 + 16) * 8 + l8]);
                float p = p0 + p1;
                p += __shfl_xor(p, 1);
                p += __shfl_xor(p, 2);
                p += __shfl_xor(p, 4);
                if (l8 == 0) lds_gh[slot] = p;
            }
            __syncthreads();   // S1

            // gates + publish (wave 0, lanes 0..15) — exempt from polling
            if (tid < 16) {
                __builtin_amdgcn_s_setprio(1);
                const int gj = g * 16 + tid;
                const float hr = lds_gh[tid]      + bh0;
                const float hz = lds_gh[16 + tid] + bh1;
                const float hn = lds_gh[32 + tid] + bh2;
                const float r = fsig(gir + hr);
                const float z = fsig(giz + hz);
                const float n = ftanh(gin + r * hn);
                const float h_new = (1.f - z) * n + z * h_own;
                h_own = h_new;
                const u64 pk = pack_h((unsigned)(t + 1), h_new);
                pub_h(h0rep, (t + 1) & 1, gj, pk);
                __hip_atomic_store(y0log + (size_t)t * HDIM + gj, pk,
                                   __ATOMIC_RELAXED, __HIP_MEMORY_SCOPE_AGENT);
                __builtin_amdgcn_s_setprio(0);
                if (t == TT - 1) out[(size_t)TT * HDIM + gj] = h_new;
            } else if (t + 1 < TT) {
                // pollers: lanes 16..511 — words 2(tid-16), +1; lanes 16..47 a 3rd
                const unsigned need = (unsigned)(t + 1);
                const u64* hp = h0rep + ((size_t)xcd * 2 + ((t + 1) & 1)) * HDIM;
                const int k = tid - 16;
                if (tid < 48) {
                    u64 v0, v1, v2;
                    poll3(hp + 2 * k, hp + 2 * k + 1, hp + 992 + k, need, v0, v1, v2);
                    float2 hv;
                    hv.x = __uint_as_float((unsigned)v0);
                    hv.y = __uint_as_float((unsigned)v1);
                    reinterpret_cast<float2*>(lds_h)[k] = hv;
                    lds_h[992 + k] = __uint_as_float((unsigned)v2);
                } else {
                    u64 v0, v1;
                    poll2(hp + 2 * k, hp + 2 * k + 1, need, v0, v1);
                    float2 hv;
                    hv.x = __uint_as_float((unsigned)v0);
                    hv.y = __uint_as_float((unsigned)v1);
                    reinterpret_cast<float2*>(lds_h)[k] = hv;
                }
            }
            gir = nir; giz = niz; gin = nin;
            __syncthreads();   // S2
        }
    } else {
        // ================= layer 1 (8 units/WG) =================
        const int g1 = blockIdx.x - L0WG;

        float4 Wlo[16], Whi[16];
        if (slot < 48) {
            const int ss = (slot < 24) ? slot : slot - 24;
            const int q = ss >> 3, jl = ss & 7;
            const float* mat = (slot < 24) ? whh1 : wih1;
            const float4* row4 = reinterpret_cast<const float4*>(
                mat + (size_t)(q * HDIM + g1 * 8 + jl) * HDIM);
#pragma unroll
            for (int k4 = 0; k4 < 16; ++k4) Wlo[k4] = row4[k4 * 8 + l8];
#pragma unroll
            for (int k4 = 0; k4 < 16; ++k4) Whi[k4] = row4[(k4 + 16) * 8 + l8];
        } else {
#pragma unroll
            for (int k4 = 0; k4 < 16; ++k4) { Wlo[k4] = float4{0,0,0,0}; Whi[k4] = float4{0,0,0,0}; }
        }

        float bh0 = 0.f, bh1 = 0.f, bh2 = 0.f;
        float bi0 = 0.f, bi1 = 0.f, bi2 = 0.f;
        float h_own = 0.f;
        if (tid < 8) {
            const int u = g1 * 8 + tid;
            bh0 = bhh1[0 * HDIM + u];
            bh1 = bhh1[1 * HDIM + u];
            bh2 = bhh1[2 * HDIM + u];
            bi0 = bih1[0 * HDIM + u];
            bi1 = bih1[1 * HDIM + u];
            bi2 = bih1[2 * HDIM + u];
        }

        lds_h[tid] = 0.f;
        lds_h[tid + SBS] = 0.f;
        // prologue: stage y(0) from the tagged log (wave 7)
        if (tid >= 448) {
            stage_y(y0log, 1u, lds_y, tid - 448);
        }
        __syncthreads();

        const float4* lh4 = reinterpret_cast<const float4*>(lds_h);
        const float4* ly4 = reinterpret_cast<const float4*>(lds_y);

        for (int t = 0; t < TT; ++t) {
            if (slot < 48) {
                const float4* s4 = (slot < 24) ? lh4 : ly4;
                float p0 = 0.f, p1 = 0.f;
#pragma unroll
                for (int k4 = 0; k4 < 16; ++k4) p0 += dot4(Wlo[k4], s4[k4 * 8 + l8]);
#pragma unroll
                for (int k4 = 0; k4 < 16; ++k4) p1 += dot4(Whi[k4], s4[(k4 + 16) * 8 + l8]);
                float p = p0 + p1;
                p += __shfl_xor(p, 1);
                p += __shfl_xor(p, 2);
                p += __shfl_xor(p, 4);
                if (l8 == 0) lds_gh[slot] = p;
            }
            __syncthreads();   // S1

            // gates + publish (lanes 0..7) — exempt from polling
            if (tid < 8) {
                __builtin_amdgcn_s_setprio(1);
                const int u = g1 * 8 + tid;
                const float hr = lds_gh[tid]      + bh0;
                const float hz = lds_gh[8 + tid]  + bh1;
                const float hn = lds_gh[16 + tid] + bh2;
                const float ir = lds_gh[24 + tid] + bi0;
                const float iz = lds_gh[32 + tid] + bi1;
                const float in_ = lds_gh[40 + tid] + bi2;
                const float r = fsig(ir + hr);
                const float z = fsig(iz + hz);
                const float n = ftanh(in_ + r * hn);
                const float h_new = (1.f - z) * n + z * h_own;
                h_own = h_new;
                pub_h(h1rep, (t + 1) & 1, u, pack_h((unsigned)(t + 1), h_new));
                __builtin_amdgcn_s_setprio(0);
                out[(size_t)t * HDIM + u] = h_new;
                if (t == TT - 1) out[(size_t)TT * HDIM + HDIM + u] = h_new;
            }

            // wave 7: stage y(t+1) from the log — exempt from h-polling
            if (tid >= 448 && t + 1 < TT) {
                stage_y(y0log + (size_t)(t + 1) * HDIM, (unsigned)(t + 2),
                        lds_y, tid - 448);
            }

            // pollers: lanes 8..447 — words 2(tid-8), +1; lanes 8..151 a 3rd
            if (tid >= 8 && tid < 448 && t + 1 < TT) {
                const unsigned need = (unsigned)(t + 1);
                const u64* hp = h1rep + ((size_t)xcd * 2 + ((t + 1) & 1)) * HDIM;
                const int k = tid - 8;
                if (tid < 152) {
                    u64 v0, v1, v2;
                    poll3(hp + 2 * k, hp + 2 * k + 1, hp + 880 + k, need, v0, v1, v2);
                    float2 hv;
                    hv.x = __uint_as_float((unsigned)v0);
                    hv.y = __uint_as_float((unsigned)v1);
                    reinterpret_cast<float2*>(lds_h)[k] = hv;
                    lds_h[880 + k] = __uint_as_float((unsigned)v2);
                } else {
                    u64 v0, v1;
                    poll2(hp + 2 * k, hp + 2 * k + 1, need, v0, v1);
                    float2 hv;
                    hv.x = __uint_as_float((unsigned)v0);
                    hv.y = __uint_as_float((unsigned)v1);
                    reinterpret_cast<float2*>(lds_h)[k] = hv;
                }
            }
            __syncthreads();   // S2
        }
    }
}

// ---------------- launch ----------------
extern "C" void kernel_launch(void* const* d_in, const int* in_sizes, int n_in,
                              void* d_out, int out_size, void* d_ws, size_t ws_size,
                              hipStream_t stream) {
    const int*   idx = (const int*)d_in[0];
    const float* emb = (const float*)d_in[1];
    const float* wih = (const float*)d_in[2];
    const float* whh = (const float*)d_in[3];
    const float* bih = (const float*)d_in[4];
    const float* bhh = (const float*)d_in[5];
    float* out = (float*)d_out;

    float* x     = (float*)d_ws;                 // [T,H]
    float* gi    = x  + (size_t)TT * HDIM;       // [T,3H]
    u64*   y0log = (u64*)(gi + (size_t)TT * 3 * HDIM);   // [T][H] tagged
    u64*   h0rep = y0log + (size_t)TT * HDIM;            // [NREP][2][H]
    u64*   h1rep = h0rep + (size_t)NREP * 2 * HDIM;      // [NREP][2][H]
    size_t zero_bytes = ((size_t)TT * HDIM + 2 * (size_t)NREP * 2 * HDIM) * 8;

    hipMemsetAsync(y0log, 0, zero_bytes, stream);

    embed_kernel<<<TT, 256, 0, stream>>>(idx, emb, x);

    const size_t wstride = (size_t)3 * HDIM * HDIM;
    const size_t bstride = (size_t)3 * HDIM;

    gemm_nt_bias<<<dim3(TT / BM, 3 * HDIM / BN), 256, 0, stream>>>(
        x, wih, bih, gi, TT, 3 * HDIM, HDIM);

    gru_pipe<<<L0WG + L1WG, SBS, 0, stream>>>(
        gi, whh, bhh,
        wih + wstride, whh + wstride, bih + bstride, bhh + bstride,
        y0log, out, h0rep, h1rep);
}

// Round 18
// 10113.325 us; speedup vs baseline: 1.4952x; 1.0502x over previous
//
#include <hip/hip_runtime.h>
#include <hip/hip_bf16.h>

// v18 = v12 verbatim (best measured: 10.085 ms total, R12).
// Structure: embed -> gemm(gi0) -> fused pipelined scan (192 WGs).
//  - L0: 64 WGs x 16 units; L1: 128 WGs x 8 units (pipelined, lag ~1 step).
//  - h exchange: 8-replica tagged u64 arrays (producer stores to all 8,
//    consumers poll replica[blockIdx&7]); concurrent 2-word polls.
//  - y0 hand-off: append-only tagged log (data-in-tag, no fences/flags).
//  - weights f32, streamed from L2 per step (measured perf-neutral vs
//    resident/LDS — bandwidth fully hidden; R14/R15).
// Per-step floor ~2.35us = L3 publish-visibility + 192-WG detect straggler
// + dot/gates/barriers. Six exchange designs landed within +-10% of this.

#define TT    4096
#define HDIM  1024
#define L0WG  64
#define L1WG  128
#define SBS   512
#define NREP  8
typedef unsigned long long u64;

// ---------------- embedding gather ----------------
__global__ void embed_kernel(const int* __restrict__ idx,
                             const float* __restrict__ emb,
                             float* __restrict__ x) {
    int t = blockIdx.x;
    int row = idx[t];
    const float4* src = reinterpret_cast<const float4*>(emb + (size_t)row * HDIM);
    float4* dst = reinterpret_cast<float4*>(x + (size_t)t * HDIM);
    dst[threadIdx.x] = src[threadIdx.x];
}

// ---------------- fp32 NT GEMM ----------------
#define BM 64
#define BN 64
#define BK 32
__global__ __launch_bounds__(256)
void gemm_nt_bias(const float* __restrict__ A,
                  const float* __restrict__ Bw,
                  const float* __restrict__ bias,
                  float* __restrict__ C,
                  int M, int N, int K) {
    __shared__ float As[BK][BM];
    __shared__ float Bs[BK][BN];
    const int tid = threadIdx.x;
    const int m0 = blockIdx.x * BM;
    const int n0 = blockIdx.y * BN;
    const int tx = tid & 15, ty = tid >> 4;
    const int lr = tid >> 3;
    const int lc = (tid & 7) * 4;

    float acc[4][4] = {};

    for (int k0 = 0; k0 < K; k0 += BK) {
#pragma unroll
        for (int pass = 0; pass < 2; ++pass) {
            int m = lr + pass * 32;
            float4 v = *reinterpret_cast<const float4*>(A + (size_t)(m0 + m) * K + k0 + lc);
            As[lc + 0][m] = v.x; As[lc + 1][m] = v.y;
            As[lc + 2][m] = v.z; As[lc + 3][m] = v.w;
            float4 u = *reinterpret_cast<const float4*>(Bw + (size_t)(n0 + m) * K + k0 + lc);
            Bs[lc + 0][m] = u.x; Bs[lc + 1][m] = u.y;
            Bs[lc + 2][m] = u.z; Bs[lc + 3][m] = u.w;
        }
        __syncthreads();
#pragma unroll
        for (int kk = 0; kk < BK; ++kk) {
            float4 a = *reinterpret_cast<const float4*>(&As[kk][ty * 4]);
            float4 b = *reinterpret_cast<const float4*>(&Bs[kk][tx * 4]);
            float av[4] = {a.x, a.y, a.z, a.w};
            float bv[4] = {b.x, b.y, b.z, b.w};
#pragma unroll
            for (int i = 0; i < 4; ++i)
#pragma unroll
                for (int j = 0; j < 4; ++j)
                    acc[i][j] = fmaf(av[i], bv[j], acc[i][j]);
        }
        __syncthreads();
    }

    float4 b4 = *reinterpret_cast<const float4*>(bias + n0 + tx * 4);
    float bb[4] = {b4.x, b4.y, b4.z, b4.w};
#pragma unroll
    for (int i = 0; i < 4; ++i) {
        int m = m0 + ty * 4 + i;
        float4 o;
        o.x = acc[i][0] + bb[0];
        o.y = acc[i][1] + bb[1];
        o.z = acc[i][2] + bb[2];
        o.w = acc[i][3] + bb[3];
        *reinterpret_cast<float4*>(C + (size_t)m * N + n0 + tx * 4) = o;
    }
}

// ---------------- helpers ----------------
__device__ __forceinline__ float dot4(float4 a, float4 b) {
    return fmaf(a.x, b.x, fmaf(a.y, b.y, fmaf(a.z, b.z, a.w * b.w)));
}
__device__ __forceinline__ float fsig(float x) { return 1.f / (1.f + __expf(-x)); }
__device__ __forceinline__ float ftanh(float x) {
    return fmaf(-2.f, 1.f / (1.f + __expf(2.f * x)), 1.f);
}
__device__ __forceinline__ u64 pack_h(unsigned seq, float h) {
    return ((u64)seq << 32) | (u64)__float_as_uint(h);
}
__device__ __forceinline__ u64 aload(const u64* p) {
    return __hip_atomic_load(p, __ATOMIC_RELAXED, __HIP_MEMORY_SCOPE_AGENT);
}
__device__ __forceinline__ u64 poll_h(const u64* p, unsigned need) {
    u64 v = aload(p);
    while ((unsigned)(v >> 32) < need) v = aload(p);
    return v;
}
// concurrent two-word poll (both loads in flight each round)
__device__ __forceinline__ void poll2(const u64* p0, const u64* p1, unsigned need,
                                      u64& v0, u64& v1) {
    v0 = aload(p0);
    v1 = aload(p1);
    while ((unsigned)(v0 >> 32) < need || (unsigned)(v1 >> 32) < need) {
        v0 = aload(p0);
        v1 = aload(p1);
    }
}
__device__ __forceinline__ void pub_h(u64* rep, int par, int idx, u64 v) {
#pragma unroll
    for (int r = 0; r < NREP; ++r)
        __hip_atomic_store(rep + ((size_t)r * 2 + par) * HDIM + idx, v,
                           __ATOMIC_RELAXED, __HIP_MEMORY_SCOPE_AGENT);
}
// stage a full y-row from the tagged log into lds (lane l owns k*64+l)
__device__ __forceinline__ void stage_y(const u64* lrow, unsigned need,
                                        float* lds_y, int l) {
    u64 v[16];
#pragma unroll
    for (int k = 0; k < 16; ++k) v[k] = aload(lrow + k * 64 + l);
#pragma unroll
    for (int k = 0; k < 16; ++k)
        while ((unsigned)(v[k] >> 32) < need) v[k] = aload(lrow + k * 64 + l);
#pragma unroll
    for (int k = 0; k < 16; ++k)
        lds_y[k * 64 + l] = __uint_as_float((unsigned)v[k]);
}

// ---------------- fused pipelined scan ----------------
__global__ __launch_bounds__(SBS, 1)
void gru_pipe(const float* __restrict__ gi0,
              const float* __restrict__ whh0,
              const float* __restrict__ bhh0,
              const float* __restrict__ wih1,
              const float* __restrict__ whh1,
              const float* __restrict__ bih1,
              const float* __restrict__ bhh1,
              u64* y0log,                  // [T][HDIM] tagged, append-only
              float* __restrict__ out,     // [T*H + 2H]
              u64* h0rep, u64* h1rep) {    // [NREP][2][HDIM] tagged
    const int tid  = threadIdx.x;
    const int slot = tid >> 3;
    const int l8   = tid & 7;
    const int xcd  = blockIdx.x & 7;

    __shared__ float lds_h[HDIM];
    __shared__ float lds_y[HDIM];
    __shared__ float lds_gh[48];

    if (blockIdx.x < L0WG) {
        // ================= layer 0 =================
        const int g = blockIdx.x;

        float4 Wlo[16], Whi[16];
        if (slot < 48) {
            const int q = slot >> 4, jl = slot & 15;
            const float4* row4 = reinterpret_cast<const float4*>(
                whh0 + (size_t)(q * HDIM + g * 16 + jl) * HDIM);
#pragma unroll
            for (int k4 = 0; k4 < 16; ++k4) Wlo[k4] = row4[k4 * 8 + l8];
#pragma unroll
            for (int k4 = 0; k4 < 16; ++k4) Whi[k4] = row4[(k4 + 16) * 8 + l8];
        } else {
#pragma unroll
            for (int k4 = 0; k4 < 16; ++k4) { Wlo[k4] = float4{0,0,0,0}; Whi[k4] = float4{0,0,0,0}; }
        }

        float bh0 = 0.f, bh1 = 0.f, bh2 = 0.f;
        float gir = 0.f, giz = 0.f, gin = 0.f;
        float h_own = 0.f;
        if (tid < 16) {
            const int gj = g * 16 + tid;
            bh0 = bhh0[0 * HDIM + gj];
            bh1 = bhh0[1 * HDIM + gj];
            bh2 = bhh0[2 * HDIM + gj];
            gir = gi0[gj];
            giz = gi0[HDIM + gj];
            gin = gi0[2 * HDIM + gj];
        }

        lds_h[tid] = 0.f;
        lds_h[tid + SBS] = 0.f;
        __syncthreads();

        const float4* lh4 = reinterpret_cast<const float4*>(lds_h);

        for (int t = 0; t < TT; ++t) {
            float nir = 0.f, niz = 0.f, nin = 0.f;
            if (tid < 16 && t + 1 < TT) {
                const float* base = gi0 + (size_t)(t + 1) * 3 * HDIM + g * 16 + tid;
                nir = base[0];
                niz = base[HDIM];
                nin = base[2 * HDIM];
            }

            if (slot < 48) {
                float p0 = 0.f, p1 = 0.f;
#pragma unroll
                for (int k4 = 0; k4 < 16; ++k4) p0 += dot4(Wlo[k4], lh4[k4 * 8 + l8]);
#pragma unroll
                for (int k4 = 0; k4 < 16; ++k4) p1 += dot4(Whi[k4], lh4[(k4 + 16) * 8 + l8]);
                float p = p0 + p1;
                p += __shfl_xor(p, 1);
                p += __shfl_xor(p, 2);
                p += __shfl_xor(p, 4);
                if (l8 == 0) lds_gh[slot] = p;
            }
            __syncthreads();   // S1

            if (tid < 16) {
                const int gj = g * 16 + tid;
                const float hr = lds_gh[tid]      + bh0;
                const float hz = lds_gh[16 + tid] + bh1;
                const float hn = lds_gh[32 + tid] + bh2;
                const float r = fsig(gir + hr);
                const float z = fsig(giz + hz);
                const float n = ftanh(gin + r * hn);
                const float h_new = (1.f - z) * n + z * h_own;
                h_own = h_new;
                const u64 pk = pack_h((unsigned)(t + 1), h_new);
                pub_h(h0rep, (t + 1) & 1, gj, pk);
                __hip_atomic_store(y0log + (size_t)t * HDIM + gj, pk,
                                   __ATOMIC_RELAXED, __HIP_MEMORY_SCOPE_AGENT);
                if (t == TT - 1) out[(size_t)TT * HDIM + gj] = h_new;
            }

            {
                const unsigned need = (unsigned)(t + 1);
                const u64* hp = h0rep + ((size_t)xcd * 2 + ((t + 1) & 1)) * HDIM;
                u64 v0, v1;
                poll2(hp + 2 * tid, hp + 2 * tid + 1, need, v0, v1);
                float2 hv;
                hv.x = __uint_as_float((unsigned)v0);
                hv.y = __uint_as_float((unsigned)v1);
                reinterpret_cast<float2*>(lds_h)[tid] = hv;
            }
            gir = nir; giz = niz; gin = nin;
            __syncthreads();   // S2
        }
    } else {
        // ================= layer 1 =================
        const int g1 = blockIdx.x - L0WG;

        float4 Wlo[16], Whi[16];
        if (slot < 48) {
            const int ss = (slot < 24) ? slot : slot - 24;
            const int q = ss >> 3, jl = ss & 7;
            const float* mat = (slot < 24) ? whh1 : wih1;
            const float4* row4 = reinterpret_cast<const float4*>(
                mat + (size_t)(q * HDIM + g1 * 8 + jl) * HDIM);
#pragma unroll
            for (int k4 = 0; k4 < 16; ++k4) Wlo[k4] = row4[k4 * 8 + l8];
#pragma unroll
            for (int k4 = 0; k4 < 16; ++k4) Whi[k4] = row4[(k4 + 16) * 8 + l8];
        } else {
#pragma unroll
            for (int k4 = 0; k4 < 16; ++k4) { Wlo[k4] = float4{0,0,0,0}; Whi[k4] = float4{0,0,0,0}; }
        }

        float bh0 = 0.f, bh1 = 0.f, bh2 = 0.f;
        float bi0 = 0.f, bi1 = 0.f, bi2 = 0.f;
        float h_own = 0.f;
        if (tid < 8) {
            const int u = g1 * 8 + tid;
            bh0 = bhh1[0 * HDIM + u];
            bh1 = bhh1[1 * HDIM + u];
            bh2 = bhh1[2 * HDIM + u];
            bi0 = bih1[0 * HDIM + u];
            bi1 = bih1[1 * HDIM + u];
            bi2 = bih1[2 * HDIM + u];
        }

        lds_h[tid] = 0.f;
        lds_h[tid + SBS] = 0.f;
        // prologue: stage y(0) from the tagged log (wave 7)
        if (tid >= 448) {
            stage_y(y0log, 1u, lds_y, tid - 448);
        }
        __syncthreads();

        const float4* lh4 = reinterpret_cast<const float4*>(lds_h);
        const float4* ly4 = reinterpret_cast<const float4*>(lds_y);

        for (int t = 0; t < TT; ++t) {
            if (slot < 48) {
                const float4* s4 = (slot < 24) ? lh4 : ly4;
                float p0 = 0.f, p1 = 0.f;
#pragma unroll
                for (int k4 = 0; k4 < 16; ++k4) p0 += dot4(Wlo[k4], s4[k4 * 8 + l8]);
#pragma unroll
                for (int k4 = 0; k4 < 16; ++k4) p1 += dot4(Whi[k4], s4[(k4 + 16) * 8 + l8]);
                float p = p0 + p1;
                p += __shfl_xor(p, 1);
                p += __shfl_xor(p, 2);
                p += __shfl_xor(p, 4);
                if (l8 == 0) lds_gh[slot] = p;
            }
            __syncthreads();   // S1

            if (tid < 8) {
                const int u = g1 * 8 + tid;
                const float hr = lds_gh[tid]      + bh0;
                const float hz = lds_gh[8 + tid]  + bh1;
                const float hn = lds_gh[16 + tid] + bh2;
                const float ir = lds_gh[24 + tid] + bi0;
                const float iz = lds_gh[32 + tid] + bi1;
                const float in_ = lds_gh[40 + tid] + bi2;
                const float r = fsig(ir + hr);
                const float z = fsig(iz + hz);
                const float n = ftanh(in_ + r * hn);
                const float h_new = (1.f - z) * n + z * h_own;
                h_own = h_new;
                pub_h(h1rep, (t + 1) & 1, u, pack_h((unsigned)(t + 1), h_new));
                out[(size_t)t * HDIM + u] = h_new;
                if (t == TT - 1) out[(size_t)TT * HDIM + HDIM + u] = h_new;
            }

            // wave 7: stage y(t+1) from the tagged log (between S1 and S2)
            if (tid >= 448 && t + 1 < TT) {
                stage_y(y0log + (size_t)(t + 1) * HDIM, (unsigned)(t + 2),
                        lds_y, tid - 448);
            }

            {
                const unsigned need = (unsigned)(t + 1);
                const u64* hp = h1rep + ((size_t)xcd * 2 + ((t + 1) & 1)) * HDIM;
                u64 v0, v1;
                poll2(hp + 2 * tid, hp + 2 * tid + 1, need, v0, v1);
                float2 hv;
                hv.x = __uint_as_float((unsigned)v0);
                hv.y = __uint_as_float((unsigned)v1);
                reinterpret_cast<float2*>(lds_h)[tid] = hv;
            }
            __syncthreads();   // S2
        }
    }
}

// ---------------- launch ----------------
extern "C" void kernel_launch(void* const* d_in, const int* in_sizes, int n_in,
                              void* d_out, int out_size, void* d_ws, size_t ws_size,
                              hipStream_t stream) {
    const int*   idx = (const int*)d_in[0];
    const float* emb = (const float*)d_in[1];
    const float* wih = (const float*)d_in[2];
    const float* whh = (const float*)d_in[3];
    const float* bih = (const float*)d_in[4];
    const float* bhh = (const float*)d_in[5];
    float* out = (float*)d_out;

    float* x     = (float*)d_ws;                 // [T,H]
    float* gi    = x  + (size_t)TT * HDIM;       // [T,3H]
    u64*   y0log = (u64*)(gi + (size_t)TT * 3 * HDIM);   // [T][H] tagged
    u64*   h0rep = y0log + (size_t)TT * HDIM;            // [NREP][2][H]
    u64*   h1rep = h0rep + (size_t)NREP * 2 * HDIM;      // [NREP][2][H]
    // y0log + replicas must be zeroed every call (tags are compared >=)
    size_t zero_bytes = ((size_t)TT * HDIM + 2 * (size_t)NREP * 2 * HDIM) * 8;

    hipMemsetAsync(y0log, 0, zero_bytes, stream);

    embed_kernel<<<TT, 256, 0, stream>>>(idx, emb, x);

    const size_t wstride = (size_t)3 * HDIM * HDIM;
    const size_t bstride = (size_t)3 * HDIM;

    gemm_nt_bias<<<dim3(TT / BM, 3 * HDIM / BN), 256, 0, stream>>>(
        x, wih, bih, gi, TT, 3 * HDIM, HDIM);

    gru_pipe<<<L0WG + L1WG, SBS, 0, stream>>>(
        gi, whh, bhh,
        wih + wstride, whh + wstride, bih + bstride, bhh + bstride,
        y0log, out, h0rep, h1rep);
}